// Round 2
// baseline (252.449 us; speedup 1.0000x reference)
//
#include <hip/hip_runtime.h>
#include <math.h>

#ifndef M_PI
#define M_PI 3.14159265358979323846
#endif

// Problem:  x (2,32,64,64,64) f32 ; weight (32,32,20,20,20) f32 ; out (2,32,64,64,64) f32
// out = idct3( zeropad( einsum('bcdhw,codhw', trunc20(dct3(x)), w) ) )
// dct/idct are linear: fwd A[20][64], inv B[64][20], computed in k_tables.

// ---------------- coefficient tables ----------------
// tab[0..1280)   : A[k][n]  k<20, n<64   (DCT-II rows, X[0] pre-halved)
// tab[1280..2560): B[m][k]  m<64, k<20   (DCT-III, c[0]*2 folded in, 1/64 scale)
__global__ __launch_bounds__(256) void k_tables(float* __restrict__ tab) {
  int i = blockIdx.x * 256 + threadIdx.x;
  if (i >= 2560) return;
  if (i < 1280) {
    int k = i >> 6, n = i & 63;
    double v = (k == 0) ? 1.0 : 2.0 * cos(M_PI * (double)(k * (2 * n + 1)) / 128.0);
    tab[i] = (float)v;
  } else {
    int j = i - 1280;
    int m = j / 20, k = j % 20;
    double v = (k == 0) ? 1.0 : cos(M_PI * (double)(k * (2 * m + 1)) / 128.0);
    tab[i] = (float)(v / 64.0);
  }
}

// ---------------- forward: W axis ----------------
// x[(bc*64+d)*64+h][64w] -> t0[row][20kw]; row = (bc*64+d)*64+h
__global__ __launch_bounds__(256) void k_dct_w(const float* __restrict__ x,
                                               const float* __restrict__ A,
                                               float* __restrict__ t0) {
  int r = blockIdx.x * 256 + threadIdx.x;            // 262144 rows
  const float4* xp = (const float4*)(x + (size_t)r * 64);
  float v[64];
#pragma unroll
  for (int j = 0; j < 16; ++j) {
    float4 q = xp[j];
    v[4 * j + 0] = q.x; v[4 * j + 1] = q.y; v[4 * j + 2] = q.z; v[4 * j + 3] = q.w;
  }
  float4* op = (float4*)(t0 + (size_t)r * 20);
#pragma unroll
  for (int j = 0; j < 5; ++j) {
    float4 q;
    float* qf = (float*)&q;
#pragma unroll
    for (int l = 0; l < 4; ++l) {
      int k = 4 * j + l;
      float acc = 0.f;
#pragma unroll
      for (int w = 0; w < 64; ++w) acc = fmaf(A[k * 64 + w], v[w], acc);
      qf[l] = acc;
    }
    op[j] = q;
  }
}

// ---------------- forward: H axis ----------------
// t0[plane][64h][20kw] -> t1[plane][20kh][20kw], plane = bc*64+d
__global__ __launch_bounds__(256) void k_dct_h(const float* __restrict__ t0,
                                               const float* __restrict__ A,
                                               float* __restrict__ t1) {
  int t = blockIdx.x * 256 + threadIdx.x;            // 81920
  int plane = t / 20, kw = t % 20;
  const float* ip = t0 + (size_t)plane * 1280 + kw;
  float v[64];
#pragma unroll
  for (int h = 0; h < 64; ++h) v[h] = ip[h * 20];
  float* op = t1 + (size_t)plane * 400 + kw;
#pragma unroll 4
  for (int k = 0; k < 20; ++k) {
    float acc = 0.f;
#pragma unroll
    for (int h = 0; h < 64; ++h) acc = fmaf(A[k * 64 + h], v[h], acc);
    op[k * 20] = acc;
  }
}

// ---------------- forward: D axis ----------------
// t1[bc][64d][400m] -> modes[bc][20kd][400m]
__global__ __launch_bounds__(256) void k_dct_d(const float* __restrict__ t1,
                                               const float* __restrict__ A,
                                               float* __restrict__ modes) {
  int t = blockIdx.x * 256 + threadIdx.x;            // 25600
  int bc = t / 400, m = t % 400;
  const float* ip = t1 + (size_t)bc * 25600 + m;
  float v[64];
#pragma unroll
  for (int d = 0; d < 64; ++d) v[d] = ip[d * 400];
  float* op = modes + (size_t)bc * 8000 + m;
#pragma unroll 4
  for (int k = 0; k < 20; ++k) {
    float acc = 0.f;
#pragma unroll
    for (int d = 0; d < 64; ++d) acc = fmaf(A[k * 64 + d], v[d], acc);
    op[k * 400] = acc;
  }
}

// ---------------- channel mix ----------------
// om[b*32+o][8000] = sum_c modes[b*32+c][m] * wgt[(c*32+o)][m]
__global__ __launch_bounds__(256) void k_mix(const float* __restrict__ modes,
                                             const float* __restrict__ wgt,
                                             float* __restrict__ om) {
  int t = blockIdx.x * 256 + threadIdx.x;            // 256000
  if (t >= 32 * 8000) return;
  int o = t / 8000, m = t % 8000;
  float acc0 = 0.f, acc1 = 0.f;
#pragma unroll 8
  for (int c = 0; c < 32; ++c) {
    float wv = wgt[(size_t)(c * 32 + o) * 8000 + m];
    acc0 = fmaf(modes[(size_t)c * 8000 + m], wv, acc0);
    acc1 = fmaf(modes[(size_t)(c + 32) * 8000 + m], wv, acc1);
  }
  om[(size_t)o * 8000 + m] = acc0;
  om[(size_t)(o + 32) * 8000 + m] = acc1;
}

// ---------------- inverse: D axis ----------------
// om[bo][20kd][400m] -> t2[bo][64d][400m]
__global__ __launch_bounds__(256) void k_idct_d(const float* __restrict__ om,
                                                const float* __restrict__ B,
                                                float* __restrict__ t2) {
  int t = blockIdx.x * 256 + threadIdx.x;            // 1638400
  int bo = t / 25600;
  int r = t % 25600;
  int d = r / 400, m = r % 400;
  const float* ip = om + (size_t)bo * 8000 + m;
  float acc = 0.f;
#pragma unroll
  for (int k = 0; k < 20; ++k) acc = fmaf(B[d * 20 + k], ip[k * 400], acc);
  t2[t] = acc;
}

// ---------------- inverse: H axis ----------------
// t2[plane][20kh][20kw] -> t3[plane][64h][20kw], plane = bo*64+d
__global__ __launch_bounds__(256) void k_idct_h(const float* __restrict__ t2,
                                                const float* __restrict__ B,
                                                float* __restrict__ t3) {
  int t = blockIdx.x * 256 + threadIdx.x;            // 81920
  int plane = t / 20, kw = t % 20;
  const float* ip = t2 + (size_t)plane * 400 + kw;
  float v[20];
#pragma unroll
  for (int k = 0; k < 20; ++k) v[k] = ip[k * 20];
  float* op = t3 + (size_t)plane * 1280 + kw;
#pragma unroll 4
  for (int h = 0; h < 64; ++h) {
    float acc = 0.f;
#pragma unroll
    for (int k = 0; k < 20; ++k) acc = fmaf(B[h * 20 + k], v[k], acc);
    op[h * 20] = acc;
  }
}

// ---------------- inverse: W axis ----------------
// t3[row][20kw] -> out[row][64w], row = (bo*64+d)*64+h
__global__ __launch_bounds__(256) void k_idct_w(const float* __restrict__ t3,
                                                const float* __restrict__ B,
                                                float* __restrict__ out) {
  int r = blockIdx.x * 256 + threadIdx.x;            // 262144 rows
  const float4* ip = (const float4*)(t3 + (size_t)r * 20);
  float v[20];
#pragma unroll
  for (int j = 0; j < 5; ++j) {
    float4 q = ip[j];
    v[4 * j + 0] = q.x; v[4 * j + 1] = q.y; v[4 * j + 2] = q.z; v[4 * j + 3] = q.w;
  }
  float4* op = (float4*)(out + (size_t)r * 64);
#pragma unroll
  for (int j = 0; j < 16; ++j) {
    float4 q;
    float* qf = (float*)&q;
#pragma unroll
    for (int l = 0; l < 4; ++l) {
      int w0 = 4 * j + l;
      float acc = 0.f;
#pragma unroll
      for (int k = 0; k < 20; ++k) acc = fmaf(B[w0 * 20 + k], v[k], acc);
      qf[l] = acc;
    }
    op[j] = q;
  }
}

extern "C" void kernel_launch(void* const* d_in, const int* in_sizes, int n_in,
                              void* d_out, int out_size, void* d_ws, size_t ws_size,
                              hipStream_t stream) {
  const float* x   = (const float*)d_in[0];   // 16,777,216 f32
  const float* wgt = (const float*)d_in[1];   //  8,192,000 f32
  float* out = (float*)d_out;                 // 16,777,216 f32
  float* ws  = (float*)d_ws;

  float* tabA  = ws;                          // 1,280
  float* tabB  = ws + 1280;                   // 1,280
  float* t0    = ws + 2560;                   // 5,242,880  (reused as t3)
  float* t1    = t0 + 5242880;                // 1,638,400  (reused as t2)
  float* modes = t1 + 1638400;                //   512,000
  float* om    = modes + 512000;              //   512,000
  float* t2 = t1;                             // t1 dead after k_dct_d
  float* t3 = t0;                             // t0 dead after k_dct_h
  // total ws use: 7,907,840 floats = 31.6 MB

  k_tables<<<10,   256, 0, stream>>>(ws);
  k_dct_w <<<1024, 256, 0, stream>>>(x, tabA, t0);
  k_dct_h <<<320,  256, 0, stream>>>(t0, tabA, t1);
  k_dct_d <<<100,  256, 0, stream>>>(t1, tabA, modes);
  k_mix   <<<1000, 256, 0, stream>>>(modes, wgt, om);
  k_idct_d<<<6400, 256, 0, stream>>>(om, tabB, t2);
  k_idct_h<<<320,  256, 0, stream>>>(t2, tabB, t3);
  k_idct_w<<<1024, 256, 0, stream>>>(t3, tabB, out);
}

// Round 3
// 229.924 us; speedup vs baseline: 1.0980x; 1.0980x over previous
//
#include <hip/hip_runtime.h>
#include <math.h>

#ifndef M_PI
#define M_PI 3.14159265358979323846
#endif

// x (2,32,64,64,64) f32 ; weight (32,32,20,20,20) f32 ; out (2,32,64,64,64) f32
// out = idct3( zeropad( einsum('bcdhw,codhw', trunc20(dct3(x)), w) ) )
// All transforms are precomputed linear maps: fwd A[20][64], inv B[64][20].
// Layouts chosen so every global STORE instruction is wave-contiguous
// (round-2 rocprof: k_idct_w had 2.7x HBM write amplification from
// 256B-strided float4 stores).

// tab[0..1280)   : A[k][n]  (DCT-II rows, X[0] pre-halved)
// tab[1280..2560): B[m][k]  (DCT-III, c[0]*2 folded, 1/64 scale)
__global__ __launch_bounds__(256) void k_tables(float* __restrict__ tab) {
  int i = blockIdx.x * 256 + threadIdx.x;
  if (i >= 2560) return;
  if (i < 1280) {
    int k = i >> 6, n = i & 63;
    double v = (k == 0) ? 1.0 : 2.0 * cos(M_PI * (double)(k * (2 * n + 1)) / 128.0);
    tab[i] = (float)v;
  } else {
    int j = i - 1280;
    int m = j / 20, k = j % 20;
    double v = (k == 0) ? 1.0 : cos(M_PI * (double)(k * (2 * m + 1)) / 128.0);
    tab[i] = (float)(v / 64.0);
  }
}

// ---- forward W:  x[row=plane*64+h][64w] -> t0T[plane][20k][64h] ----
// wave = 64 consecutive rows = one plane's h-dim -> each store instr is
// 256B contiguous. A[k*64+w] wave-uniform -> s_load.
__global__ __launch_bounds__(256) void k_dct_w(const float* __restrict__ x,
                                               const float* __restrict__ A,
                                               float* __restrict__ t0T) {
  int r = blockIdx.x * 256 + threadIdx.x;        // 262144 rows
  int plane = r >> 6, h = r & 63;
  const float4* xp = (const float4*)(x + (size_t)r * 64);
  float v[64];
#pragma unroll
  for (int j = 0; j < 16; ++j) {
    float4 q = xp[j];
    v[4 * j] = q.x; v[4 * j + 1] = q.y; v[4 * j + 2] = q.z; v[4 * j + 3] = q.w;
  }
  float* op = t0T + (size_t)plane * 1280 + h;
#pragma unroll 4
  for (int k = 0; k < 20; ++k) {
    float acc = 0.f;
#pragma unroll
    for (int w = 0; w < 64; ++w) acc = fmaf(A[k * 64 + w], v[w], acc);
    op[k * 64] = acc;                            // lanes: h consecutive
  }
}

// ---- forward H:  t0T[plane][kw][64h] -> t1[plane][kh*20+kw] ----
// thread = (khalf, plane, kw); reads 16 contiguous float4; 10 outputs.
__global__ __launch_bounds__(256) void k_dct_h(const float* __restrict__ t0T,
                                               const float* __restrict__ A,
                                               float* __restrict__ t1) {
  int tid = blockIdx.x * 256 + threadIdx.x;      // 163840
  int khalf = __builtin_amdgcn_readfirstlane(tid / 81920);
  int t2 = tid % 81920;
  int plane = t2 / 20, kw = t2 % 20;
  const float4* ip = (const float4*)(t0T + (size_t)plane * 1280 + kw * 64);
  float v[64];
#pragma unroll
  for (int j = 0; j < 16; ++j) {
    float4 q = ip[j];
    v[4 * j] = q.x; v[4 * j + 1] = q.y; v[4 * j + 2] = q.z; v[4 * j + 3] = q.w;
  }
  float* op = t1 + (size_t)plane * 400 + kw;
#pragma unroll 2
  for (int kk = 0; kk < 10; ++kk) {
    int kh = khalf * 10 + kk;                    // wave-uniform -> s_load A
    float acc = 0.f;
#pragma unroll
    for (int h = 0; h < 64; ++h) acc = fmaf(A[kh * 64 + h], v[h], acc);
    op[kh * 20] = acc;
  }
}

// ---- forward D:  t1[bc][64d][400m] -> modes[bc][20k][400m] ----
// LDS-tiled: block = (bc, 64-wide m tile). 448 blocks (vs 100 before).
__global__ __launch_bounds__(256) void k_dct_d(const float* __restrict__ t1,
                                               const float* __restrict__ A,
                                               float* __restrict__ modes) {
  __shared__ float ts[64 * 68];
  int bc = blockIdx.x / 7, tile = blockIdx.x % 7;
  int mbase = tile * 64;
  int t = threadIdx.x;
#pragma unroll
  for (int rep = 0; rep < 4; ++rep) {            // 1024 float4 loads
    int idx = rep * 256 + t;
    int d = idx >> 4, mq = idx & 15;
    float4 q = make_float4(0.f, 0.f, 0.f, 0.f);
    if (mbase + 4 * mq + 3 < 400)
      q = *(const float4*)(t1 + (size_t)bc * 25600 + d * 400 + mbase + 4 * mq);
    *(float4*)(ts + d * 68 + 4 * mq) = q;
  }
  __syncthreads();
#pragma unroll
  for (int rep = 0; rep < 5; ++rep) {            // 1280 outputs
    int idx = rep * 256 + t;
    int k = __builtin_amdgcn_readfirstlane(idx >> 6);  // wave-uniform
    int m = idx & 63;
    float acc = 0.f;
#pragma unroll
    for (int d = 0; d < 64; ++d) acc = fmaf(A[k * 64 + d], ts[d * 68 + m], acc);
    if (mbase + m < 400)
      modes[(size_t)bc * 8000 + k * 400 + mbase + m] = acc;
  }
}

// ---- channel mix (coalesced over m) ----
__global__ __launch_bounds__(256) void k_mix(const float* __restrict__ modes,
                                             const float* __restrict__ wgt,
                                             float* __restrict__ om) {
  int t = blockIdx.x * 256 + threadIdx.x;        // 256000
  int o = t / 8000, m = t % 8000;
  float acc0 = 0.f, acc1 = 0.f;
#pragma unroll 8
  for (int c = 0; c < 32; ++c) {
    float wv = wgt[(size_t)(c * 32 + o) * 8000 + m];
    acc0 = fmaf(modes[(size_t)c * 8000 + m], wv, acc0);
    acc1 = fmaf(modes[(size_t)(c + 32) * 8000 + m], wv, acc1);
  }
  om[(size_t)o * 8000 + m] = acc0;
  om[(size_t)(o + 32) * 8000 + m] = acc1;
}

// ---- inverse D:  om[bo][20kd][kh*20+kw] -> t2T[bo][64d][kw*20+kh] ----
// Output transposed (kw,kh) so k_idct_h reads contiguously. om is 2MB L2-hot.
__global__ __launch_bounds__(256) void k_idct_d(const float* __restrict__ om,
                                                const float* __restrict__ B,
                                                float* __restrict__ t2T) {
  int t = blockIdx.x * 256 + threadIdx.x;        // 1638400
  int bo = t / 25600, r = t % 25600;
  int d = r / 400, m2 = r % 400;
  int kw = m2 / 20, kh = m2 % 20;
  const float* ip = om + (size_t)bo * 8000 + kh * 20 + kw;
  float acc = 0.f;
#pragma unroll
  for (int kd = 0; kd < 20; ++kd) acc = fmaf(B[d * 20 + kd], ip[kd * 400], acc);
  t2T[t] = acc;                                  // lanes consecutive
}

// ---- inverse H:  t2T[plane][kw][20kh] -> t3[plane][64h][20kw] ----
__global__ __launch_bounds__(256) void k_idct_h(const float* __restrict__ t2T,
                                                const float* __restrict__ B,
                                                float* __restrict__ t3) {
  int tid = blockIdx.x * 256 + threadIdx.x;      // 163840
  int hhalf = __builtin_amdgcn_readfirstlane(tid / 81920);
  int t2 = tid % 81920;
  int plane = t2 / 20, kw = t2 % 20;
  const float4* ip = (const float4*)(t2T + (size_t)plane * 400 + kw * 20);
  float v[20];
#pragma unroll
  for (int j = 0; j < 5; ++j) {
    float4 q = ip[j];
    v[4 * j] = q.x; v[4 * j + 1] = q.y; v[4 * j + 2] = q.z; v[4 * j + 3] = q.w;
  }
  float* op = t3 + (size_t)plane * 1280 + kw;
#pragma unroll 4
  for (int hh = 0; hh < 32; ++hh) {
    int h = hhalf * 32 + hh;                     // wave-uniform -> s_load B
    float acc = 0.f;
#pragma unroll
    for (int k = 0; k < 20; ++k) acc = fmaf(B[h * 20 + k], v[k], acc);
    op[h * 20] = acc;
  }
}

// ---- inverse W:  t3[plane][64h][20kw] -> out[plane][64h][64w] ----
// LDS-staged transpose: compute into lds[w][h], flush with contiguous
// float4 stores (kills the 2.7x write amplification).
__global__ __launch_bounds__(256) void k_idct_w(const float* __restrict__ t3,
                                                const float* __restrict__ B,
                                                float* __restrict__ out) {
  __shared__ float lds[64 * 65];
  int plane = blockIdx.x;                        // 4096
  int t = threadIdx.x;
  int lane = t & 63;
  int g = __builtin_amdgcn_readfirstlane(t >> 6);  // wave's w-segment
  const float4* ip = (const float4*)(t3 + ((size_t)plane * 64 + lane) * 20);
  float v[20];
#pragma unroll
  for (int j = 0; j < 5; ++j) {
    float4 q = ip[j];
    v[4 * j] = q.x; v[4 * j + 1] = q.y; v[4 * j + 2] = q.z; v[4 * j + 3] = q.w;
  }
#pragma unroll
  for (int j = 0; j < 16; ++j) {
    int w = g * 16 + j;                          // wave-uniform -> s_load B
    float acc = 0.f;
#pragma unroll
    for (int k = 0; k < 20; ++k) acc = fmaf(B[w * 20 + k], v[k], acc);
    lds[w * 65 + lane] = acc;                    // lanes consecutive
  }
  __syncthreads();
  float* ob = out + (size_t)plane * 4096;
#pragma unroll
  for (int rep = 0; rep < 4; ++rep) {            // 1024 float4 stores
    int f4 = rep * 256 + t;
    int h = f4 >> 4, wq = f4 & 15;
    float4 q;
    q.x = lds[(4 * wq + 0) * 65 + h];
    q.y = lds[(4 * wq + 1) * 65 + h];
    q.z = lds[(4 * wq + 2) * 65 + h];
    q.w = lds[(4 * wq + 3) * 65 + h];
    *(float4*)(ob + h * 64 + 4 * wq) = q;        // 1KB contiguous per wave
  }
}

extern "C" void kernel_launch(void* const* d_in, const int* in_sizes, int n_in,
                              void* d_out, int out_size, void* d_ws, size_t ws_size,
                              hipStream_t stream) {
  const float* x   = (const float*)d_in[0];
  const float* wgt = (const float*)d_in[1];
  float* out = (float*)d_out;
  float* ws  = (float*)d_ws;

  float* tabA  = ws;                     // 1,280
  float* tabB  = ws + 1280;              // 1,280
  float* t0T   = ws + 2560;              // 5,242,880  (4096 planes * 1280)
  float* t1    = t0T + 5242880;          // 1,638,400  (4096 * 400)
  float* modes = t1 + 1638400;           //   512,000
  float* om    = modes + 512000;         //   512,000
  float* t2T = t1;                       // t1 dead after k_dct_d
  float* t3  = t0T;                      // t0T dead after k_dct_h
  // total ws: 7,907,840 floats = 31.6 MB

  k_tables<<<10,   256, 0, stream>>>(ws);
  k_dct_w <<<1024, 256, 0, stream>>>(x, tabA, t0T);
  k_dct_h <<<640,  256, 0, stream>>>(t0T, tabA, t1);
  k_dct_d <<<448,  256, 0, stream>>>(t1, tabA, modes);
  k_mix   <<<1000, 256, 0, stream>>>(modes, wgt, om);
  k_idct_d<<<6400, 256, 0, stream>>>(om, tabB, t2T);
  k_idct_h<<<640,  256, 0, stream>>>(t2T, tabB, t3);
  k_idct_w<<<4096, 256, 0, stream>>>(t3, tabB, out);
}

// Round 4
// 225.093 us; speedup vs baseline: 1.1215x; 1.0215x over previous
//
#include <hip/hip_runtime.h>
#include <math.h>

#ifndef M_PI
#define M_PI 3.14159265358979323846
#endif

// x (2,32,64,64,64) f32 ; weight (32,32,20,20,20) f32 ; out (2,32,64,64,64) f32
// out = idct3( zeropad( einsum('bcdhw,codhw', trunc20(dct3(x)), w) ) )
// Precomputed linear maps: fwd A[20][64], inv B[64][20].
// Round-4: kill scattered-transaction kernels. k_idct_d was issuing 33M
// 4B-at-1600B-stride loads; now LDS-slab staged, fully coalesced.
// k_dct_w input now staged via LDS (was 64-lines-per-instr row loads).

// tab[0..1280)   : A[k][n]  (DCT-II rows, X[0] pre-halved)
// tab[1280..2560): B[m][k]  (DCT-III, c[0]*2 folded, 1/64 scale)
__global__ __launch_bounds__(256) void k_tables(float* __restrict__ tab) {
  int i = blockIdx.x * 256 + threadIdx.x;
  if (i >= 2560) return;
  if (i < 1280) {
    int k = i >> 6, n = i & 63;
    double v = (k == 0) ? 1.0 : 2.0 * cos(M_PI * (double)(k * (2 * n + 1)) / 128.0);
    tab[i] = (float)v;
  } else {
    int j = i - 1280;
    int m = j / 20, k = j % 20;
    double v = (k == 0) ? 1.0 : cos(M_PI * (double)(k * (2 * m + 1)) / 128.0);
    tab[i] = (float)(v / 64.0);
  }
}

// ---- forward W: x[plane][64h][64w] -> t0T[plane][20kw][64h] ----
// P0: coalesced float4 plane load -> LDS [h][w] (pad 65).
// P1: thread (g=t>>6, h=t&63): row h -> regs (stride-65 LDS reads,
//     conflict-free), 5 outputs kw=g*5+j, A via wave-uniform s_load,
//     stores lane-contiguous over h.
__global__ __launch_bounds__(256) void k_dct_w(const float* __restrict__ x,
                                               const float* __restrict__ A,
                                               float* __restrict__ t0T) {
  __shared__ float xl[64 * 65];
  int plane = blockIdx.x;                        // 4096
  int t = threadIdx.x;
  const float4* xp = (const float4*)(x + (size_t)plane * 4096);
#pragma unroll
  for (int rep = 0; rep < 4; ++rep) {
    int idx = rep * 256 + t;                     // 1024 float4s
    float4 q = xp[idx];
    int h = idx >> 4, wq = idx & 15;
    float* dst = xl + h * 65 + 4 * wq;
    dst[0] = q.x; dst[1] = q.y; dst[2] = q.z; dst[3] = q.w;
  }
  __syncthreads();
  int h = t & 63;
  int g = t >> 6;                                // wave-uniform
  float v[64];
#pragma unroll
  for (int w = 0; w < 64; ++w) v[w] = xl[h * 65 + w];
  float* op = t0T + (size_t)plane * 1280 + h;
#pragma unroll
  for (int j = 0; j < 5; ++j) {
    int k = g * 5 + j;
    float acc = 0.f;
#pragma unroll
    for (int w = 0; w < 64; ++w) acc = fmaf(A[k * 64 + w], v[w], acc);
    op[k * 64] = acc;                            // 256B contiguous per wave
  }
}

// ---- forward H: t0T[plane][kw][64h] -> t1[plane][kh*20+kw] ----
__global__ __launch_bounds__(256) void k_dct_h(const float* __restrict__ t0T,
                                               const float* __restrict__ A,
                                               float* __restrict__ t1) {
  int tid = blockIdx.x * 256 + threadIdx.x;      // 163840
  int khalf = __builtin_amdgcn_readfirstlane(tid / 81920);
  int t2 = tid % 81920;
  int plane = t2 / 20, kw = t2 % 20;
  const float4* ip = (const float4*)(t0T + (size_t)plane * 1280 + kw * 64);
  float v[64];
#pragma unroll
  for (int j = 0; j < 16; ++j) {
    float4 q = ip[j];
    v[4 * j] = q.x; v[4 * j + 1] = q.y; v[4 * j + 2] = q.z; v[4 * j + 3] = q.w;
  }
  float* op = t1 + (size_t)plane * 400 + kw;
#pragma unroll 2
  for (int kk = 0; kk < 10; ++kk) {
    int kh = khalf * 10 + kk;                    // wave-uniform -> s_load A
    float acc = 0.f;
#pragma unroll
    for (int h = 0; h < 64; ++h) acc = fmaf(A[kh * 64 + h], v[h], acc);
    op[kh * 20] = acc;
  }
}

// ---- forward D: t1[bc][64d][400m] -> modes[bc][20k][400m] ----
__global__ __launch_bounds__(256) void k_dct_d(const float* __restrict__ t1,
                                               const float* __restrict__ A,
                                               float* __restrict__ modes) {
  __shared__ float ts[64 * 68];
  int bc = blockIdx.x / 7, tile = blockIdx.x % 7;
  int mbase = tile * 64;
  int t = threadIdx.x;
#pragma unroll
  for (int rep = 0; rep < 4; ++rep) {
    int idx = rep * 256 + t;
    int d = idx >> 4, mq = idx & 15;
    float4 q = make_float4(0.f, 0.f, 0.f, 0.f);
    if (mbase + 4 * mq + 3 < 400)
      q = *(const float4*)(t1 + (size_t)bc * 25600 + d * 400 + mbase + 4 * mq);
    *(float4*)(ts + d * 68 + 4 * mq) = q;
  }
  __syncthreads();
#pragma unroll
  for (int rep = 0; rep < 5; ++rep) {
    int idx = rep * 256 + t;
    int k = __builtin_amdgcn_readfirstlane(idx >> 6);  // wave-uniform
    int m = idx & 63;
    float acc = 0.f;
#pragma unroll
    for (int d = 0; d < 64; ++d) acc = fmaf(A[k * 64 + d], ts[d * 68 + m], acc);
    if (mbase + m < 400)
      modes[(size_t)bc * 8000 + k * 400 + mbase + m] = acc;
  }
}

// ---- channel mix ----
__global__ __launch_bounds__(256) void k_mix(const float* __restrict__ modes,
                                             const float* __restrict__ wgt,
                                             float* __restrict__ om) {
  int t = blockIdx.x * 256 + threadIdx.x;        // 256000
  int o = t / 8000, m = t % 8000;
  float acc0 = 0.f, acc1 = 0.f;
#pragma unroll 8
  for (int c = 0; c < 32; ++c) {
    float wv = wgt[(size_t)(c * 32 + o) * 8000 + m];
    acc0 = fmaf(modes[(size_t)c * 8000 + m], wv, acc0);
    acc1 = fmaf(modes[(size_t)(c + 32) * 8000 + m], wv, acc1);
  }
  om[(size_t)o * 8000 + m] = acc0;
  om[(size_t)(o + 32) * 8000 + m] = acc1;
}

// ---- inverse D: om[bo][20kd][kh*20+kw] -> t2T[bo][64d][kw*20+kh] ----
// Block = (bo, 4-d group). om slab (32KB) staged in LDS as
// [kd][kh*21+kw] (pad 21, coprime 32 -> the (kh,kw)->(kw,kh) transpose
// read is conflict-free). All global loads/stores lane-contiguous.
__global__ __launch_bounds__(256) void k_idct_d(const float* __restrict__ om,
                                                const float* __restrict__ B,
                                                float* __restrict__ t2T) {
  __shared__ float om_l[20 * 420];
  __shared__ float B_l[1280];
  int bo = blockIdx.x >> 4;                      // 64
  int dgrp = blockIdx.x & 15;                    // 16 groups of 4 d
  int t = threadIdx.x;
#pragma unroll
  for (int rep = 0; rep < 5; ++rep) {
    int idx = rep * 256 + t;
    if (idx < 1280) B_l[idx] = B[idx];
  }
  const float4* ip = (const float4*)(om + (size_t)bo * 8000);
#pragma unroll
  for (int rep = 0; rep < 8; ++rep) {
    int gi = rep * 256 + t;                      // 2000 float4s
    if (gi < 2000) {
      float4 q = ip[gi];
      int f = 4 * gi;
      int kd = f / 400, r = f % 400;
      int kh = r / 20, kw = r % 20;              // kw in {0,4,8,12,16}
      float* dst = om_l + kd * 420 + kh * 21 + kw;
      dst[0] = q.x; dst[1] = q.y; dst[2] = q.z; dst[3] = q.w;
    }
  }
  __syncthreads();
  float* opb = t2T + (size_t)bo * 25600 + (size_t)dgrp * 4 * 400;
#pragma unroll
  for (int rep = 0; rep < 7; ++rep) {
    int idx = rep * 256 + t;                     // 1600 outputs
    if (idx < 1600) {
      int dloc = idx / 400, m2 = idx % 400;
      int kw = m2 / 20, kh = m2 % 20;            // m2 = kw*20+kh
      int d = dgrp * 4 + dloc;
      float acc = 0.f;
#pragma unroll
      for (int kd = 0; kd < 20; ++kd)
        acc = fmaf(B_l[d * 20 + kd], om_l[kd * 420 + kh * 21 + kw], acc);
      opb[idx] = acc;                            // lane-contiguous
    }
  }
}

// ---- inverse H: t2T[plane][kw][20kh] -> t3[plane][64h][20kw] ----
__global__ __launch_bounds__(256) void k_idct_h(const float* __restrict__ t2T,
                                                const float* __restrict__ B,
                                                float* __restrict__ t3) {
  int tid = blockIdx.x * 256 + threadIdx.x;      // 163840
  int hhalf = __builtin_amdgcn_readfirstlane(tid / 81920);
  int t2 = tid % 81920;
  int plane = t2 / 20, kw = t2 % 20;
  const float4* ip = (const float4*)(t2T + (size_t)plane * 400 + kw * 20);
  float v[20];
#pragma unroll
  for (int j = 0; j < 5; ++j) {
    float4 q = ip[j];
    v[4 * j] = q.x; v[4 * j + 1] = q.y; v[4 * j + 2] = q.z; v[4 * j + 3] = q.w;
  }
  float* op = t3 + (size_t)plane * 1280 + kw;
#pragma unroll 4
  for (int hh = 0; hh < 32; ++hh) {
    int h = hhalf * 32 + hh;                     // wave-uniform -> s_load B
    float acc = 0.f;
#pragma unroll
    for (int k = 0; k < 20; ++k) acc = fmaf(B[h * 20 + k], v[k], acc);
    op[h * 20] = acc;
  }
}

// ---- inverse W: t3[plane][64h][20kw] -> out[plane][64h][64w] ----
__global__ __launch_bounds__(256) void k_idct_w(const float* __restrict__ t3,
                                                const float* __restrict__ B,
                                                float* __restrict__ out) {
  __shared__ float lds[64 * 65];
  int plane = blockIdx.x;                        // 4096
  int t = threadIdx.x;
  int lane = t & 63;
  int g = __builtin_amdgcn_readfirstlane(t >> 6);
  const float4* ip = (const float4*)(t3 + ((size_t)plane * 64 + lane) * 20);
  float v[20];
#pragma unroll
  for (int j = 0; j < 5; ++j) {
    float4 q = ip[j];
    v[4 * j] = q.x; v[4 * j + 1] = q.y; v[4 * j + 2] = q.z; v[4 * j + 3] = q.w;
  }
#pragma unroll
  for (int j = 0; j < 16; ++j) {
    int w = g * 16 + j;                          // wave-uniform -> s_load B
    float acc = 0.f;
#pragma unroll
    for (int k = 0; k < 20; ++k) acc = fmaf(B[w * 20 + k], v[k], acc);
    lds[w * 65 + lane] = acc;
  }
  __syncthreads();
  float* ob = out + (size_t)plane * 4096;
#pragma unroll
  for (int rep = 0; rep < 4; ++rep) {
    int f4 = rep * 256 + t;
    int h = f4 >> 4, wq = f4 & 15;
    float4 q;
    q.x = lds[(4 * wq + 0) * 65 + h];
    q.y = lds[(4 * wq + 1) * 65 + h];
    q.z = lds[(4 * wq + 2) * 65 + h];
    q.w = lds[(4 * wq + 3) * 65 + h];
    *(float4*)(ob + h * 64 + 4 * wq) = q;        // 1KB contiguous per wave
  }
}

extern "C" void kernel_launch(void* const* d_in, const int* in_sizes, int n_in,
                              void* d_out, int out_size, void* d_ws, size_t ws_size,
                              hipStream_t stream) {
  const float* x   = (const float*)d_in[0];
  const float* wgt = (const float*)d_in[1];
  float* out = (float*)d_out;
  float* ws  = (float*)d_ws;

  float* tabA  = ws;                     // 1,280
  float* tabB  = ws + 1280;              // 1,280
  float* t0T   = ws + 2560;              // 5,242,880
  float* t1    = t0T + 5242880;          // 1,638,400
  float* modes = t1 + 1638400;           //   512,000
  float* om    = modes + 512000;         //   512,000
  float* t2T = t1;                       // t1 dead after k_dct_d
  float* t3  = t0T;                      // t0T dead after k_dct_h

  k_tables<<<10,   256, 0, stream>>>(ws);
  k_dct_w <<<4096, 256, 0, stream>>>(x, tabA, t0T);
  k_dct_h <<<640,  256, 0, stream>>>(t0T, tabA, t1);
  k_dct_d <<<448,  256, 0, stream>>>(t1, tabA, modes);
  k_mix   <<<1000, 256, 0, stream>>>(modes, wgt, om);
  k_idct_d<<<1024, 256, 0, stream>>>(om, tabB, t2T);
  k_idct_h<<<640,  256, 0, stream>>>(t2T, tabB, t3);
  k_idct_w<<<4096, 256, 0, stream>>>(t3, tabB, out);
}

// Round 7
// 179.791 us; speedup vs baseline: 1.4041x; 1.2520x over previous
//
#include <hip/hip_runtime.h>
#include <math.h>

#ifndef M_PI
#define M_PI 3.14159265358979323846
#endif

// x (2,32,64,64,64) f32 ; weight (32,32,20,20,20) f32 ; out (2,32,64,64,64) f32
// out = idct3( zeropad( einsum('bcdhw,codhw', trunc20(dct3(x)), w) ) )
// Linear maps: fwd A[20][64], inv B[64][20] (precomputed in k_tables).
//
// 5 kernels:
//   k_fwd_wh : per-plane fused W+H DCT   x -> t1[plane][kh*20+kw]
//   k_dct_d  : D-axis DCT                t1 -> modes[bc][kd][400]
//   k_mix    : channel mix               modes,wgt -> om
//   k_inv_hw : per-plane fused D+H+W inv om -> out
// Round-5 bug (fixed): k_inv_hw step1 decoded om's mode index as kw*20+kh;
// it is kh*20+kw. Result was a per-plane (h,w) transpose, absmax 0.31.
// Round-4 lesson kept: coefficient row indices must be provably wave-uniform
// (readfirstlane / blockIdx) so the compiler emits s_loads.

__global__ __launch_bounds__(256) void k_tables(float* __restrict__ tab) {
  int i = blockIdx.x * 256 + threadIdx.x;
  if (i >= 2560) return;
  if (i < 1280) {
    int k = i >> 6, n = i & 63;
    double v = (k == 0) ? 1.0 : 2.0 * cos(M_PI * (double)(k * (2 * n + 1)) / 128.0);
    tab[i] = (float)v;
  } else {
    int j = i - 1280;
    int m = j / 20, k = j % 20;
    double v = (k == 0) ? 1.0 : cos(M_PI * (double)(k * (2 * m + 1)) / 128.0);
    tab[i] = (float)(v / 64.0);
  }
}

// ---- fused forward W+H, block = plane (bc*64+d), 4096 blocks ----
__global__ __launch_bounds__(256) void k_fwd_wh(const float* __restrict__ x,
                                                const float* __restrict__ tabA,
                                                float* __restrict__ t1) {
  __shared__ float xl[64 * 65];
  __shared__ float t0l[20 * 67];
  __shared__ float A_l[20 * 68];
  int plane = blockIdx.x;
  int t = threadIdx.x;
  const float4* xp = (const float4*)(x + (size_t)plane * 4096);
#pragma unroll
  for (int rep = 0; rep < 4; ++rep) {
    int idx = rep * 256 + t;
    float4 q = xp[idx];
    int h = idx >> 4, wq = idx & 15;
    float* dst = xl + h * 65 + 4 * wq;
    dst[0] = q.x; dst[1] = q.y; dst[2] = q.z; dst[3] = q.w;
  }
#pragma unroll
  for (int rep = 0; rep < 5; ++rep) {
    int idx = rep * 256 + t;
    if (idx < 1280) A_l[(idx >> 6) * 68 + (idx & 63)] = tabA[idx];
  }
  __syncthreads();
  {  // phase B: contract w.  k wave-uniform -> A s_load.
    int h = t & 63;
    int g = __builtin_amdgcn_readfirstlane(t >> 6);
    float v[64];
#pragma unroll
    for (int w = 0; w < 64; ++w) v[w] = xl[h * 65 + w];
#pragma unroll
    for (int j = 0; j < 5; ++j) {
      int k = g * 5 + j;
      float acc = 0.f;
#pragma unroll
      for (int w = 0; w < 64; ++w) acc = fmaf(tabA[k * 64 + w], v[w], acc);
      t0l[k * 67 + h] = acc;
    }
  }
  __syncthreads();
  if (t < 80) {  // phase C: contract h. 80 threads x 5 outputs.
    int kw = t >> 2, khg = t & 3;
    float v[64];
#pragma unroll
    for (int h = 0; h < 64; ++h) v[h] = t0l[kw * 67 + h];
    float* op = t1 + (size_t)plane * 400 + kw;
#pragma unroll
    for (int j = 0; j < 5; ++j) {
      int kh = khg * 5 + j;
      float acc = 0.f;
#pragma unroll
      for (int h = 0; h < 64; ++h) acc = fmaf(A_l[kh * 68 + h], v[h], acc);
      op[kh * 20] = acc;                         // t1[plane][kh*20+kw]
    }
  }
}

// ---- forward D: t1[bc][64d][400m] -> modes[bc][20k][400m] ----
__global__ __launch_bounds__(256) void k_dct_d(const float* __restrict__ t1,
                                               const float* __restrict__ A,
                                               float* __restrict__ modes) {
  __shared__ float ts[64 * 68];
  int bc = blockIdx.x / 7, tile = blockIdx.x % 7;
  int mbase = tile * 64;
  int t = threadIdx.x;
#pragma unroll
  for (int rep = 0; rep < 4; ++rep) {
    int idx = rep * 256 + t;
    int d = idx >> 4, mq = idx & 15;
    float4 q = make_float4(0.f, 0.f, 0.f, 0.f);
    if (mbase + 4 * mq + 3 < 400)
      q = *(const float4*)(t1 + (size_t)bc * 25600 + d * 400 + mbase + 4 * mq);
    *(float4*)(ts + d * 68 + 4 * mq) = q;
  }
  __syncthreads();
#pragma unroll
  for (int rep = 0; rep < 5; ++rep) {
    int idx = rep * 256 + t;
    int k = __builtin_amdgcn_readfirstlane(idx >> 6);  // wave-uniform
    int m = idx & 63;
    float acc = 0.f;
#pragma unroll
    for (int d = 0; d < 64; ++d) acc = fmaf(A[k * 64 + d], ts[d * 68 + m], acc);
    if (mbase + m < 400)
      modes[(size_t)bc * 8000 + k * 400 + mbase + m] = acc;
  }
}

// ---- channel mix ----
__global__ __launch_bounds__(256) void k_mix(const float* __restrict__ modes,
                                             const float* __restrict__ wgt,
                                             float* __restrict__ om) {
  int t = blockIdx.x * 256 + threadIdx.x;        // 256000
  int o = t / 8000, m = t % 8000;
  float acc0 = 0.f, acc1 = 0.f;
#pragma unroll 8
  for (int c = 0; c < 32; ++c) {
    float wv = wgt[(size_t)(c * 32 + o) * 8000 + m];
    acc0 = fmaf(modes[(size_t)c * 8000 + m], wv, acc0);
    acc1 = fmaf(modes[(size_t)(c + 32) * 8000 + m], wv, acc1);
  }
  om[(size_t)o * 8000 + m] = acc0;
  om[(size_t)(o + 32) * 8000 + m] = acc1;
}

// ---- fused inverse D+H+W, block = plane (bo*64+d), 4096 blocks ----
// step1: t2l[kw][kh] = sum_kd B[d][kd]*om[bo][kd][kh*20+kw]  (om idx = kh*20+kw!)
// step2: t3l[h][kw]  = sum_kh B21[h][kh]*t2l[kw][kh]
// step3: ldsT[w][h]  = sum_kw B[w][kw]*t3l[h][kw]
// flush: coalesced float4 stores.
__global__ __launch_bounds__(256) void k_inv_hw(const float* __restrict__ om,
                                                const float* __restrict__ tabB,
                                                float* __restrict__ out) {
  __shared__ float B21[64 * 21];
  __shared__ float t2l[20 * 21];
  __shared__ float t3l[64 * 21];
  __shared__ float ldsT[64 * 65];
  int plane = blockIdx.x;
  int bo = plane >> 6, d = plane & 63;
  int t = threadIdx.x;
#pragma unroll
  for (int rep = 0; rep < 5; ++rep) {
    int idx = rep * 256 + t;
    if (idx < 1280) { int m = idx / 20; B21[m * 21 + (idx - 20 * m)] = tabB[idx]; }
  }
  if (t < 200) {  // step1: B row d via s_load; om reads lane-consecutive.
    const float* ob = om + (size_t)bo * 8000;
#pragma unroll
    for (int rr = 0; rr < 2; ++rr) {
      int idx = t + rr * 200;
      int kh = idx / 20, kw = idx % 20;          // om mode idx = kh*20+kw
      float acc = 0.f;
#pragma unroll
      for (int kd = 0; kd < 20; ++kd)
        acc = fmaf(tabB[d * 20 + kd], ob[kd * 400 + idx], acc);
      t2l[kw * 21 + kh] = acc;                   // store as [kw][kh]
    }
  }
  __syncthreads();
  {  // step2: 8 hseg x 20 kw threads (kw>=20 lanes idle)
    int kw = t & 31, hseg = t >> 5;
    if (kw < 20) {
      float v[20];
#pragma unroll
      for (int kh = 0; kh < 20; ++kh) v[kh] = t2l[kw * 21 + kh];
#pragma unroll
      for (int i = 0; i < 8; ++i) {
        int h = hseg * 8 + i;
        float acc = 0.f;
#pragma unroll
        for (int kh = 0; kh < 20; ++kh) acc = fmaf(B21[h * 21 + kh], v[kh], acc);
        t3l[h * 21 + kw] = acc;
      }
    }
  }
  __syncthreads();
  {  // step3: w wave-uniform -> B row s_load
    int h = t & 63;
    int g = __builtin_amdgcn_readfirstlane(t >> 6);
    float v[20];
#pragma unroll
    for (int kw = 0; kw < 20; ++kw) v[kw] = t3l[h * 21 + kw];
#pragma unroll
    for (int j = 0; j < 16; ++j) {
      int w = g * 16 + j;
      float acc = 0.f;
#pragma unroll
      for (int kw = 0; kw < 20; ++kw) acc = fmaf(tabB[w * 20 + kw], v[kw], acc);
      ldsT[w * 65 + h] = acc;
    }
  }
  __syncthreads();
  float* ob2 = out + (size_t)plane * 4096;
#pragma unroll
  for (int rep = 0; rep < 4; ++rep) {
    int f4 = rep * 256 + t;
    int h = f4 >> 4, wq = f4 & 15;
    float4 q;
    q.x = ldsT[(4 * wq + 0) * 65 + h];
    q.y = ldsT[(4 * wq + 1) * 65 + h];
    q.z = ldsT[(4 * wq + 2) * 65 + h];
    q.w = ldsT[(4 * wq + 3) * 65 + h];
    *(float4*)(ob2 + h * 64 + 4 * wq) = q;       // 1KB contiguous per wave
  }
}

extern "C" void kernel_launch(void* const* d_in, const int* in_sizes, int n_in,
                              void* d_out, int out_size, void* d_ws, size_t ws_size,
                              hipStream_t stream) {
  const float* x   = (const float*)d_in[0];
  const float* wgt = (const float*)d_in[1];
  float* out = (float*)d_out;
  float* ws  = (float*)d_ws;

  float* tabA  = ws;                     // 1,280
  float* tabB  = ws + 1280;              // 1,280
  float* t1    = ws + 2560;              // 1,638,400 (4096 x 400)
  float* modes = t1 + 1638400;           //   512,000
  float* om    = modes + 512000;         //   512,000
  // total ws: 2,665,440 floats = 10.7 MB

  k_tables<<<10,   256, 0, stream>>>(ws);
  k_fwd_wh<<<4096, 256, 0, stream>>>(x, tabA, t1);
  k_dct_d <<<448,  256, 0, stream>>>(t1, tabA, modes);
  k_mix   <<<1000, 256, 0, stream>>>(modes, wgt, om);
  k_inv_hw<<<4096, 256, 0, stream>>>(om, tabB, out);
}